// Round 12
// baseline (1003.120 us; speedup 1.0000x reference)
//
#include <hip/hip_runtime.h>

typedef unsigned int u32;

#define NPTS 65536
#define G    48
#define NC   (G*G*G)          // 110592 cells
#define CPT  (NC/1024)        // 108 cells per scan thread (exact)

// ws byte offsets (total 3,866,896 B < 4 MB, proven backed in r5-r7)
#define BBOX_OFF 0u                            // 12 u32: [minA3,minB3, maxA3,maxB3]
#define CNTA_OFF 256u
#define CNTB_OFF (CNTA_OFF + NC*4u)
#define OFFA_OFF (CNTB_OFF + NC*4u)
#define OFFB_OFF (OFFA_OFF + (NC+1u)*4u)
#define SRTA_OFF ((OFFB_OFF + (NC+1u)*4u + 15u) & ~15u)
#define SRTB_OFF (SRTA_OFF + NPTS*16u)

// order-preserving float <-> uint transform (for atomicMin/Max bbox)
__device__ __forceinline__ u32 f2o(float f) {
    u32 u = __float_as_uint(f);
    return (u & 0x80000000u) ? ~u : (u | 0x80000000u);
}
__device__ __forceinline__ float o2f(u32 v) {
    u32 u = (v & 0x80000000u) ? (v ^ 0x80000000u) : ~v;
    return __uint_as_float(u);
}

struct GP { float lox, loy, loz, ivx, ivy, ivz, smin; };

// bb -> this cloud's min triple; matching max triple lives at bb[6..8]
__device__ __forceinline__ GP make_gp(const u32* bb) {
    GP g;
    g.lox = o2f(bb[0]); g.loy = o2f(bb[1]); g.loz = o2f(bb[2]);
    const float ex = fmaxf(o2f(bb[6]) - g.lox, 1e-20f);
    const float ey = fmaxf(o2f(bb[7]) - g.loy, 1e-20f);
    const float ez = fmaxf(o2f(bb[8]) - g.loz, 1e-20f);
    g.ivx = (float)G / ex; g.ivy = (float)G / ey; g.ivz = (float)G / ez;
    g.smin = fminf(ex, fminf(ey, ez)) * (1.0f / (float)G);
    return g;
}

__device__ __forceinline__ int clampi(int v, int lo, int hi) {
    return v < lo ? lo : (v > hi ? hi : v);
}

__device__ __forceinline__ int cell_of(const GP& g, float x, float y, float z,
                                       int& cx, int& cy, int& cz) {
    cx = clampi((int)((x - g.lox) * g.ivx), 0, G - 1);
    cy = clampi((int)((y - g.loy) * g.ivy), 0, G - 1);
    cz = clampi((int)((z - g.loz) * g.ivz), 0, G - 1);
    return (cz * G + cy) * G + cx;
}

// ---- 1. bounding boxes of both clouds (64 blocks per cloud) ----
__global__ __launch_bounds__(256) void bbox_kernel(
    const float* __restrict__ A, const float* __restrict__ B, u32* __restrict__ bbox)
{
    const int blk   = blockIdx.x;          // 0..127
    const int cloud = blk >> 6;
    const float* __restrict__ P = cloud ? B : A;
    const int start = (blk & 63) * (NPTS / 64);   // 1024 pts per block

    u32 tmin[3] = {0xFFFFFFFFu, 0xFFFFFFFFu, 0xFFFFFFFFu};
    u32 tmax[3] = {0u, 0u, 0u};
    for (int i = start + threadIdx.x; i < start + NPTS / 64; i += 256) {
#pragma unroll
        for (int d = 0; d < 3; ++d) {
            const u32 v = f2o(P[i * 3 + d]);
            tmin[d] = min(tmin[d], v);
            tmax[d] = max(tmax[d], v);
        }
    }
    __shared__ u32 smin[3], smax[3];
    if (threadIdx.x < 3) { smin[threadIdx.x] = 0xFFFFFFFFu; smax[threadIdx.x] = 0u; }
    __syncthreads();
#pragma unroll
    for (int d = 0; d < 3; ++d) {
        atomicMin(&smin[d], tmin[d]);
        atomicMax(&smax[d], tmax[d]);
    }
    __syncthreads();
    if (threadIdx.x < 3) {
        atomicMin(&bbox[cloud * 3 + threadIdx.x], smin[threadIdx.x]);
        atomicMax(&bbox[6 + cloud * 3 + threadIdx.x], smax[threadIdx.x]);
    }
}

// ---- 2. per-cell histogram ----
__global__ __launch_bounds__(256) void count_kernel(
    const float* __restrict__ A, const float* __restrict__ B, unsigned char* __restrict__ ws)
{
    const int i = blockIdx.x * 256 + threadIdx.x;   // 0..131071
    const int cloud = i >= NPTS;
    const int p = i & (NPTS - 1);
    const float* __restrict__ P = cloud ? B : A;
    const u32* bb = (const u32*)(ws + BBOX_OFF) + cloud * 3;
    u32* cnt = (u32*)(ws + (cloud ? CNTB_OFF : CNTA_OFF));
    const GP g = make_gp(bb);
    int cx, cy, cz;
    const int c = cell_of(g, P[p * 3], P[p * 3 + 1], P[p * 3 + 2], cx, cy, cz);
    atomicAdd(&cnt[c], 1u);
}

// ---- 3. exclusive scan (one block per cloud) ----
__global__ __launch_bounds__(1024) void scan_kernel(unsigned char* __restrict__ ws)
{
    const int cloud = blockIdx.x;
    const u32* cnt = (const u32*)(ws + (cloud ? CNTB_OFF : CNTA_OFF));
    u32* off = (u32*)(ws + (cloud ? OFFB_OFF : OFFA_OFF));
    const int t = threadIdx.x;

    u32 s = 0;
    for (int k = 0; k < CPT; ++k) s += cnt[t * CPT + k];

    __shared__ u32 lds[1024];
    lds[t] = s;
    __syncthreads();
    for (int o = 1; o < 1024; o <<= 1) {
        const u32 v = (t >= o) ? lds[t - o] : 0u;
        __syncthreads();
        lds[t] += v;
        __syncthreads();
    }
    u32 run = lds[t] - s;   // exclusive base for this chunk
    for (int k = 0; k < CPT; ++k) {
        const int c = t * CPT + k;
        off[c] = run;
        run += cnt[c];
    }
    if (t == 1023) off[NC] = run;   // = 65536
}

// ---- 4. scatter into cell-sorted order (cnt doubles as down-cursor) ----
__global__ __launch_bounds__(256) void scatter_kernel(
    const float* __restrict__ A, const float* __restrict__ B, unsigned char* __restrict__ ws)
{
    const int i = blockIdx.x * 256 + threadIdx.x;
    const int cloud = i >= NPTS;
    const int p = i & (NPTS - 1);
    const float* __restrict__ P = cloud ? B : A;
    const u32* bb = (const u32*)(ws + BBOX_OFF) + cloud * 3;
    u32* cnt = (u32*)(ws + (cloud ? CNTB_OFF : CNTA_OFF));
    const u32* off = (const u32*)(ws + (cloud ? OFFB_OFF : OFFA_OFF));
    float4* srt = (float4*)(ws + (cloud ? SRTB_OFF : SRTA_OFF));

    const GP g = make_gp(bb);
    const float x = P[p * 3], y = P[p * 3 + 1], z = P[p * 3 + 2];
    int cx, cy, cz;
    const int c = cell_of(g, x, y, z, cx, cy, cz);
    const u32 old = atomicSub(&cnt[c], 1u);     // count .. 1, unique per point
    srt[off[c] + old - 1u] = make_float4(x, y, z, 0.0f);
}

// ---- 5. ring-search NN for every query of both directions + mean-reduce ----
__global__ __launch_bounds__(256) void query_kernel(
    const unsigned char* __restrict__ ws, float* __restrict__ out)
{
    const int i = blockIdx.x * 256 + threadIdx.x;   // 0..131071
    const int dirB = i >= NPTS;          // 0: queries=sortedA, DB=B ; 1: queries=sortedB, DB=A
    const int qi = i & (NPTS - 1);

    const u32* bb = (const u32*)(ws + BBOX_OFF) + (dirB ? 0 : 3);   // DB cloud's bbox
    const u32* off = (const u32*)(ws + (dirB ? OFFA_OFF : OFFB_OFF));
    const float4* __restrict__ dbp = (const float4*)(ws + (dirB ? SRTA_OFF : SRTB_OFF));
    const float4* __restrict__ qp  = (const float4*)(ws + (dirB ? SRTB_OFF : SRTA_OFF));

    const GP g = make_gp(bb);
    const float4 q = qp[qi];
    int cx, cy, cz;
    cell_of(g, q.x, q.y, q.z, cx, cy, cz);

    float best = 3.4e38f;
    for (int r = 0; r < G; ++r) {
        if (r >= 1) {
            const float rb = (float)(r - 1) * g.smin;   // lower bound to ring r
            if (rb * rb >= best) break;
        }
        for (int dz = -r; dz <= r; ++dz) {
            const int z = cz + dz;
            if ((unsigned)z >= G) continue;
            for (int dy = -r; dy <= r; ++dy) {
                const int y = cy + dy;
                if ((unsigned)y >= G) continue;
                const bool face = (dz == -r || dz == r || dy == -r || dy == r);
                const int step = face ? 1 : 2 * r;      // interior rows: only dx = +/-r
                for (int dx = -r; dx <= r; dx += step) {
                    const int x = cx + dx;
                    if ((unsigned)x >= G) continue;
                    const int c = (z * G + y) * G + x;
                    const u32 s0 = off[c], s1 = off[c + 1];
                    for (u32 k = s0; k < s1; ++k) {
                        const float4 p = dbp[k];
                        const float ddx = q.x - p.x;
                        const float ddy = q.y - p.y;
                        const float ddz = q.z - p.z;
                        best = fminf(best, fmaf(ddx, ddx, fmaf(ddy, ddy, ddz * ddz)));
                    }
                }
            }
        }
    }

    // sum(best) / NPTS accumulated into out
    float v = best;
#pragma unroll
    for (int o = 32; o > 0; o >>= 1)
        v += __shfl_down(v, o, 64);
    __shared__ float ws2[4];
    const int lane = threadIdx.x & 63;
    const int wid  = threadIdx.x >> 6;
    if (lane == 0) ws2[wid] = v;
    __syncthreads();
    if (threadIdx.x == 0)
        atomicAdd(out, (ws2[0] + ws2[1] + ws2[2] + ws2[3]) * (1.0f / (float)NPTS));
}

// ============================================================================
extern "C" void kernel_launch(void* const* d_in, const int* in_sizes, int n_in,
                              void* d_out, int out_size, void* d_ws, size_t ws_size,
                              hipStream_t stream)
{
    const float* A = (const float*)d_in[0];   // pc0 (65536,3) f32
    const float* B = (const float*)d_in[1];   // pc1 (65536,3) f32
    float* out = (float*)d_out;               // scalar f32
    unsigned char* ws = (unsigned char*)d_ws; // needs 3.87 MB (ws >= 4 MB, r5-r7)

    hipMemsetAsync(ws + BBOX_OFF, 0xFF, 24, stream);          // mins  -> 0xFFFFFFFF
    hipMemsetAsync(ws + BBOX_OFF + 24, 0x00, 24, stream);     // maxs  -> 0
    hipMemsetAsync(ws + CNTA_OFF, 0, 2u * NC * 4u, stream);   // cntA + cntB (contiguous)
    hipMemsetAsync(out, 0, sizeof(float), stream);

    bbox_kernel   <<<128, 256, 0, stream>>>(A, B, (u32*)(ws + BBOX_OFF));
    count_kernel  <<<512, 256, 0, stream>>>(A, B, ws);
    scan_kernel   <<<2, 1024, 0, stream>>>(ws);
    scatter_kernel<<<512, 256, 0, stream>>>(A, B, ws);
    query_kernel  <<<512, 256, 0, stream>>>(ws, out);
}